// Round 10
// baseline (280.680 us; speedup 1.0000x reference)
//
#include <hip/hip_runtime.h>
#include <hip/hip_bf16.h>
#include <stdint.h>

typedef __bf16 bf16x8 __attribute__((ext_vector_type(8)));
typedef float  f32x4  __attribute__((ext_vector_type(4)));
typedef __hip_bfloat16 bf16_t;

#define D_MODEL 1024
#define NH 16
#define DH 64
#define BB 2
#define SS 2048
#define MTOT (BB*SS)   /* 4096 */
#define NQT (SS/64)    /* 32 q-tiles per (b,h) */

#define GBM 128
#define GBN 64
#define GBK 64

// ---------------------------------------------------------------------------
// fp32 -> bf16 convert for q,k,v (one launch, 3 tensors)
// ---------------------------------------------------------------------------
__global__ void cvt_qkv_kernel(const float* __restrict__ q, const float* __restrict__ k,
                               const float* __restrict__ v, bf16_t* __restrict__ dst) {
  const int n1v = MTOT * D_MODEL / 4;  // float4 count per tensor
  int tid = blockIdx.x * blockDim.x + threadIdx.x;
  int stride = gridDim.x * blockDim.x;
  for (int i = tid; i < 3 * n1v; i += stride) {
    int which = i / n1v;
    int j = i - which * n1v;
    const float4* src = (const float4*)(which == 0 ? q : (which == 1 ? k : v));
    float4 f = src[j];
    union { bf16_t h[4]; short4 s4; } u;
    u.h[0] = __float2bfloat16(f.x);
    u.h[1] = __float2bfloat16(f.y);
    u.h[2] = __float2bfloat16(f.z);
    u.h[3] = __float2bfloat16(f.w);
    ((short4*)dst)[(size_t)which * n1v + j] = u.s4;
  }
}

// ---------------------------------------------------------------------------
// W [K][N] fp32  ->  Wt [N][K] bf16   (z = 0..3 selects Wq,Wk,Wv,Wo)
// ---------------------------------------------------------------------------
__global__ void transpose_w_kernel(const float* __restrict__ W0, const float* __restrict__ W1,
                                   const float* __restrict__ W2, const float* __restrict__ W3,
                                   bf16_t* __restrict__ WtAll) {
  __shared__ float tile[32][33];
  const int z = blockIdx.z;
  const float* W = (z == 0) ? W0 : (z == 1) ? W1 : (z == 2) ? W2 : W3;
  bf16_t* Wt = WtAll + (size_t)z * D_MODEL * D_MODEL;
  const int tx = threadIdx.x, ty = threadIdx.y;
  const int bx = blockIdx.x, by = blockIdx.y;
#pragma unroll
  for (int i = 0; i < 4; ++i)
    tile[ty + i * 8][tx] = W[(size_t)(by * 32 + ty + i * 8) * D_MODEL + bx * 32 + tx];
  __syncthreads();
#pragma unroll
  for (int i = 0; i < 4; ++i)
    Wt[(size_t)(bx * 32 + ty + i * 8) * D_MODEL + by * 32 + tx] =
        __float2bfloat16(tile[tx][ty + i * 8]);
}

// ---------------------------------------------------------------------------
// GEMM mainloop: C[128x64] tile. 4 waves 2x2 over (2x64 M, 2x32 N), each
// wave 64x32 = 4x2 frags. global_load_lds width-16 staging.
// ---------------------------------------------------------------------------
__device__ __forceinline__ void g2lds16(const bf16_t* g, bf16_t* l) {
  __builtin_amdgcn_global_load_lds((__attribute__((address_space(1))) void*)(g),
                                   (__attribute__((address_space(3))) void*)(l), 16, 0, 0);
}

__device__ __forceinline__ void gemm_tile_mainloop(const bf16_t* __restrict__ A,
                                                   const bf16_t* __restrict__ Bt,
                                                   bf16_t* As, bf16_t* Bs,
                                                   int m0, int n0, f32x4 acc[4][2]) {
  const int tid = threadIdx.x;
  const int wv = tid >> 6, ln = tid & 63;
  const int wr = wv >> 1, wc = wv & 1;
  const int lr = ln & 15, lg = ln >> 4;

#pragma unroll
  for (int mi = 0; mi < 4; ++mi)
#pragma unroll
    for (int ni = 0; ni < 2; ++ni)
      acc[mi][ni] = (f32x4){0.f, 0.f, 0.f, 0.f};

  for (int kt = 0; kt < D_MODEL / GBK; ++kt) {
    // stage A (128x64 = 16 chunks) and B (64x64 = 8 chunks); 6 chunks/wave
#pragma unroll
    for (int c = 0; c < 6; ++c) {
      int chunk = wv * 6 + c;
      int row8 = ln >> 3;
      int col = (ln & 7) * 8;
      if (chunk < 16) {
        g2lds16(A  + (size_t)(m0 + chunk * 8 + row8) * D_MODEL + kt * GBK + col,
                As + chunk * 8 * GBK);
      } else {
        g2lds16(Bt + (size_t)(n0 + (chunk - 16) * 8 + row8) * D_MODEL + kt * GBK + col,
                Bs + (chunk - 16) * 8 * GBK);
      }
    }
    __syncthreads();
#pragma unroll
    for (int ks = 0; ks < 2; ++ks) {
      bf16x8 af[4], bfr[2];
#pragma unroll
      for (int mi = 0; mi < 4; ++mi)
        af[mi] = *(const bf16x8*)(As + (size_t)(wr * 64 + mi * 16 + lr) * GBK + ks * 32 + lg * 8);
#pragma unroll
      for (int ni = 0; ni < 2; ++ni)
        bfr[ni] = *(const bf16x8*)(Bs + (size_t)(wc * 32 + ni * 16 + lr) * GBK + ks * 32 + lg * 8);
#pragma unroll
      for (int mi = 0; mi < 4; ++mi)
#pragma unroll
        for (int ni = 0; ni < 2; ++ni)
          acc[mi][ni] = __builtin_amdgcn_mfma_f32_16x16x32_bf16(af[mi], bfr[ni], acc[mi][ni], 0, 0, 0);
    }
    __syncthreads();
  }
}

// ---------------------------------------------------------------------------
// Q/K projection GEMM: z=0 -> Q (x 1/8 softmax scale folded), z=1 -> K.
// Row-major bf16 stores, coalesced.
// ---------------------------------------------------------------------------
__global__ __launch_bounds__(256)
void qk_proj_kernel(const bf16_t* __restrict__ Aq, const bf16_t* __restrict__ Ak,
                    const bf16_t* __restrict__ WtAll,
                    const float* __restrict__ bq, const float* __restrict__ bk,
                    bf16_t* __restrict__ Qg, bf16_t* __restrict__ Kg) {
  __shared__ bf16_t As[GBM * GBK];
  __shared__ bf16_t Bs[GBN * GBK];
  const int z = blockIdx.z;
  const bf16_t* A = (z == 0) ? Aq : Ak;
  const bf16_t* Bt = WtAll + (size_t)z * D_MODEL * D_MODEL;
  const float* bias = (z == 0) ? bq : bk;
  bf16_t* Out = (z == 0) ? Qg : Kg;
  const float scale = (z == 0) ? 0.125f : 1.0f;  // fold 1/sqrt(DH) into Q
  const int m0 = blockIdx.y * GBM, n0 = blockIdx.x * GBN;

  f32x4 acc[4][2];
  gemm_tile_mainloop(A, Bt, As, Bs, m0, n0, acc);

  const int tid = threadIdx.x;
  const int wv = tid >> 6, ln = tid & 63;
  const int wr = wv >> 1, wc = wv & 1;
  const int lr = ln & 15, lg = ln >> 4;

#pragma unroll
  for (int mi = 0; mi < 4; ++mi) {
#pragma unroll
    for (int ni = 0; ni < 2; ++ni) {
      int ncol = n0 + wc * 32 + ni * 16 + lr;
      float bsv = bias[ncol];
#pragma unroll
      for (int j = 0; j < 4; ++j) {
        int mrow = m0 + wr * 64 + mi * 16 + lg * 4 + j;
        Out[(size_t)mrow * D_MODEL + ncol] = __float2bfloat16((acc[mi][ni][j] + bsv) * scale);
      }
    }
  }
}

// ---------------------------------------------------------------------------
// V^T projection GEMM (R10): Vt[d][s_glob] = Wv^T @ Av^T + bv.
// A = Wt_v (row-major [d][k]), B^T = Av (row-major [s_glob][k]).
// Row-major coalesced stores — replaces the R9 2B-stride-4KB scatter.
// ---------------------------------------------------------------------------
__global__ __launch_bounds__(256)
void vt_proj_kernel(const bf16_t* __restrict__ Wtv, const bf16_t* __restrict__ Av,
                    const float* __restrict__ bv, bf16_t* __restrict__ Vt) {
  __shared__ bf16_t As[GBM * GBK];
  __shared__ bf16_t Bs[GBN * GBK];
  const int m0 = blockIdx.y * GBM, n0 = blockIdx.x * GBN;

  f32x4 acc[4][2];
  gemm_tile_mainloop(Wtv, Av, As, Bs, m0, n0, acc);

  const int tid = threadIdx.x;
  const int wv = tid >> 6, ln = tid & 63;
  const int wr = wv >> 1, wc = wv & 1;
  const int lr = ln & 15, lg = ln >> 4;

#pragma unroll
  for (int mi = 0; mi < 4; ++mi) {
#pragma unroll
    for (int ni = 0; ni < 2; ++ni) {
      int ncol = n0 + wc * 32 + ni * 16 + lr;
#pragma unroll
      for (int j = 0; j < 4; ++j) {
        int mrow = m0 + wr * 64 + mi * 16 + lg * 4 + j;   // d row
        Vt[(size_t)mrow * MTOT + ncol] = __float2bfloat16(acc[mi][ni][j] + bv[mrow]);
      }
    }
  }
}

// ---------------------------------------------------------------------------
// Output GEMM: ctx[M][K] bf16 @ Wo^T [N][K] bf16 + bo -> fp32 out [M][N]
// ---------------------------------------------------------------------------
__global__ __launch_bounds__(256)
void out_gemm_kernel(const bf16_t* __restrict__ Ctx, const bf16_t* __restrict__ Wto,
                     const float* __restrict__ bo, float* __restrict__ out) {
  __shared__ bf16_t As[GBM * GBK];
  __shared__ bf16_t Bs[GBN * GBK];
  const int m0 = blockIdx.y * GBM, n0 = blockIdx.x * GBN;

  f32x4 acc[4][2];
  gemm_tile_mainloop(Ctx, Wto, As, Bs, m0, n0, acc);

  const int tid = threadIdx.x;
  const int wv = tid >> 6, ln = tid & 63;
  const int wr = wv >> 1, wc = wv & 1;
  const int lr = ln & 15, lg = ln >> 4;

#pragma unroll
  for (int mi = 0; mi < 4; ++mi) {
#pragma unroll
    for (int ni = 0; ni < 2; ++ni) {
      int ncol = n0 + wc * 32 + ni * 16 + lr;
      float bsv = bo[ncol];
#pragma unroll
      for (int j = 0; j < 4; ++j) {
        int mrow = m0 + wr * 64 + mi * 16 + lg * 4 + j;
        out[(size_t)mrow * D_MODEL + ncol] = acc[mi][ni][j] + bsv;
      }
    }
  }
}

// ---------------------------------------------------------------------------
// Flash attention, causal — SWAPPED-QK^T structure (R8), V stride = MTOT,
// Q pre-scaled in projection.
// ---------------------------------------------------------------------------
__device__ __forceinline__ uint32_t pack2bf(float a, float b) {
  union { __hip_bfloat16 h; unsigned short u; } ua, ub;
  ua.h = __float2bfloat16(a);
  ub.h = __float2bfloat16(b);
  return (uint32_t)ua.u | ((uint32_t)ub.u << 16);
}

#define PSTRIDE 44  /* dwords per P row: conflict-tuned, 16B-multiple (176B) */

__device__ __forceinline__ void attn_run(
    f32x4 acc_o[2][4], f32x4 acc_l[2], float m_run[2],
    const bf16x8 qf[2][2], const bf16_t* Kbase, const bf16_t* Vbase,
    uint32_t (*P32)[PSTRIDE], int q0, int t0, int t1, int lr, int lg, bf16x8 onesf) {
  // prologue: K fragments for first tile
  bf16x8 kf_cur[2][4];
#pragma unroll
  for (int ks = 0; ks < 2; ++ks)
#pragma unroll
    for (int kb = 0; kb < 4; ++kb)
      kf_cur[ks][kb] = *(const bf16x8*)(Kbase + (size_t)(t0 * 64 + kb * 16 + lr) * D_MODEL + ks * 32 + lg * 8);

  for (int t = t0; t < t1; ++t) {
    const int kv0 = t * 64;
    f32x4 sc[2][4];
#pragma unroll
    for (int qi = 0; qi < 2; ++qi)
#pragma unroll
      for (int kb = 0; kb < 4; ++kb) sc[qi][kb] = (f32x4){0.f, 0.f, 0.f, 0.f};

    // S^T = K Q^T : C[kv][q], q-col = lane&15
    __builtin_amdgcn_s_setprio(1);
#pragma unroll
    for (int ks = 0; ks < 2; ++ks) {
#pragma unroll
      for (int kb = 0; kb < 4; ++kb) {
        sc[0][kb] = __builtin_amdgcn_mfma_f32_16x16x32_bf16(kf_cur[ks][kb], qf[0][ks], sc[0][kb], 0, 0, 0);
        sc[1][kb] = __builtin_amdgcn_mfma_f32_16x16x32_bf16(kf_cur[ks][kb], qf[1][ks], sc[1][kb], 0, 0, 0);
      }
    }
    __builtin_amdgcn_s_setprio(0);

    // prefetch K(t+1)
    bf16x8 kf_nxt[2][4];
    if (t + 1 < t1) {
#pragma unroll
      for (int ks = 0; ks < 2; ++ks)
#pragma unroll
        for (int kb = 0; kb < 4; ++kb)
          kf_nxt[ks][kb] = *(const bf16x8*)(Kbase + (size_t)(kv0 + 64 + kb * 16 + lr) * D_MODEL + ks * 32 + lg * 8);
    }
    // prefetch V(t): V^T fragment, row d = db*16+lr, k = kv
    bf16x8 vf[2][4];
#pragma unroll
    for (int ks = 0; ks < 2; ++ks)
#pragma unroll
      for (int db = 0; db < 4; ++db)
        vf[ks][db] = *(const bf16x8*)(Vbase + (size_t)(db * 16 + lr) * MTOT + kv0 + ks * 32 + lg * 8);

    // causal mask: kc = kv0+16kb+4lg+r, qc = q0+qi*16+lr
    if (kv0 + 63 > q0) {
#pragma unroll
      for (int qi = 0; qi < 2; ++qi) {
        int qc = q0 + qi * 16 + lr;
#pragma unroll
        for (int kb = 0; kb < 4; ++kb)
#pragma unroll
          for (int r = 0; r < 4; ++r) {
            int kc = kv0 + kb * 16 + 4 * lg + r;
            if (kc > qc) sc[qi][kb][r] = -1e30f;
          }
      }
    }

    // lane-local softmax per q-column
#pragma unroll
    for (int qi = 0; qi < 2; ++qi) {
      float vm = sc[qi][0][0];
#pragma unroll
      for (int kb = 0; kb < 4; ++kb)
#pragma unroll
        for (int r = 0; r < 4; ++r) vm = fmaxf(vm, sc[qi][kb][r]);
      vm = fmaxf(vm, __shfl_xor(vm, 16, 64));
      vm = fmaxf(vm, __shfl_xor(vm, 32, 64));
      float mo = m_run[qi];
      float mn = fmaxf(mo, vm);
      float scl = __expf(mo - mn);
      m_run[qi] = mn;
#pragma unroll
      for (int kb = 0; kb < 4; ++kb)
#pragma unroll
        for (int hh = 0; hh < 2; ++hh) {
          float p0 = __expf(sc[qi][kb][2 * hh]     - mn);
          float p1 = __expf(sc[qi][kb][2 * hh + 1] - mn);
          P32[qi * 16 + lr][8 * kb + 2 * lg + hh] = pack2bf(p0, p1);
        }
#pragma unroll
      for (int r = 0; r < 4; ++r) acc_l[qi][r] *= scl;
#pragma unroll
      for (int db = 0; db < 4; ++db)
#pragma unroll
        for (int r = 0; r < 4; ++r) acc_o[qi][db][r] *= scl;
    }

    // wave-internal LDS turnaround (rule #18 discipline)
    asm volatile("s_waitcnt lgkmcnt(0)" ::: "memory");
    __builtin_amdgcn_sched_barrier(0);

    // P^T fragments: B-operand needs [k=kv=32ks+8lg+j][col=q=lane&15]
    bf16x8 pb[2][2];
#pragma unroll
    for (int qi = 0; qi < 2; ++qi)
#pragma unroll
      for (int ks = 0; ks < 2; ++ks)
        pb[qi][ks] = *(const bf16x8*)&P32[qi * 16 + lr][16 * ks + 4 * lg];

    // O^T += V^T P^T ; l += ones * P^T
    __builtin_amdgcn_s_setprio(1);
#pragma unroll
    for (int ks = 0; ks < 2; ++ks) {
#pragma unroll
      for (int qi = 0; qi < 2; ++qi) {
        acc_l[qi] = __builtin_amdgcn_mfma_f32_16x16x32_bf16(onesf, pb[qi][ks], acc_l[qi], 0, 0, 0);
#pragma unroll
        for (int db = 0; db < 4; ++db)
          acc_o[qi][db] = __builtin_amdgcn_mfma_f32_16x16x32_bf16(vf[ks][db], pb[qi][ks], acc_o[qi][db], 0, 0, 0);
      }
    }
    __builtin_amdgcn_s_setprio(0);

    if (t + 1 < t1) {
#pragma unroll
      for (int ks = 0; ks < 2; ++ks)
#pragma unroll
        for (int kb = 0; kb < 4; ++kb)
          kf_cur[ks][kb] = kf_nxt[ks][kb];
    }
  }
}

__device__ __forceinline__ void attn_load_q(bf16x8 qf[2][2], const bf16_t* Qbase,
                                            int q0, int lr, int lg) {
#pragma unroll
  for (int qi = 0; qi < 2; ++qi)
#pragma unroll
    for (int ks = 0; ks < 2; ++ks)
      qf[qi][ks] = *(const bf16x8*)(Qbase + (size_t)(q0 + qi * 16 + lr) * D_MODEL + ks * 32 + lg * 8);
}

__device__ __forceinline__ void attn_init(f32x4 acc_o[2][4], f32x4 acc_l[2], float m_run[2]) {
#pragma unroll
  for (int qi = 0; qi < 2; ++qi) {
#pragma unroll
    for (int db = 0; db < 4; ++db) acc_o[qi][db] = (f32x4){0.f, 0.f, 0.f, 0.f};
    acc_l[qi] = (f32x4){0.f, 0.f, 0.f, 0.f};
    m_run[qi] = -1e30f;
  }
}

// O^T regs -> bf16 LDS bounce -> coalesced row-major store (64B segments)
__device__ __forceinline__ void store_ctx_tile(
    uint32_t (*P32)[PSTRIDE], const f32x4 acc_o[2][4], const f32x4 acc_l[2],
    bf16_t* __restrict__ Ctx, int b, int h, int q0, int ln, int lr, int lg) {
#pragma unroll
  for (int qi = 0; qi < 2; ++qi) {
    float rl = 1.0f / acc_l[qi][0];
#pragma unroll
    for (int db = 0; db < 4; ++db)
#pragma unroll
      for (int hh = 0; hh < 2; ++hh)
        P32[qi * 16 + lr][8 * db + 2 * lg + hh] =
            pack2bf(acc_o[qi][db][2 * hh] * rl, acc_o[qi][db][2 * hh + 1] * rl);
  }
  asm volatile("s_waitcnt lgkmcnt(0)" ::: "memory");
  __builtin_amdgcn_sched_barrier(0);
#pragma unroll
  for (int c = 0; c < 4; ++c) {
    int row = (ln >> 2) + 16 * (c >> 1);
    int dwc = (ln & 3) * 4 + 16 * (c & 1);
    bf16x8 v = *(const bf16x8*)&P32[row][dwc];
    *(bf16x8*)(Ctx + (size_t)(b * SS + q0 + row) * D_MODEL + h * DH + dwc * 2) = v;
  }
}

__global__ __launch_bounds__(256)
void attn_kernel(const bf16_t* __restrict__ Qg, const bf16_t* __restrict__ Kg,
                 const bf16_t* __restrict__ Vt, bf16_t* __restrict__ Ctx) {
  __shared__ __align__(16) uint32_t P32[4][32][PSTRIDE];
  __shared__ __align__(16) float O_part[2][32][68];   // partial O^T, [q][d]+pad
  __shared__ float ml_part[2][32][2];                 // [q][0]=m, [1]=l
  const int bh = blockIdx.x;
  const int pp = blockIdx.y;
  const int b = bh >> 4, h = bh & 15;
  const int wv = threadIdx.x >> 6, ln = threadIdx.x & 63;
  const int lr = ln & 15, lg = ln >> 4;

  const int qt_lo = pp, qt_hi = NQT - 1 - pp;
  const int h0 = 16 - pp;                 // high tile KV split point
  const int rh = wv & 1;                  // row half within the 64-row tile

  const size_t qkbase = (size_t)b * SS * D_MODEL + (size_t)h * DH;
  const bf16_t* Qbase = Qg + qkbase;
  const bf16_t* Kbase = Kg + qkbase;
  const bf16_t* Vbase = Vt + (size_t)(h * DH) * MTOT + b * SS;

  bf16x8 onesf;
#pragma unroll
  for (int j = 0; j < 8; ++j) onesf[j] = (__bf16)1.0f;

  bf16x8 qf[2][2];
  f32x4 acc_o[2][4];
  f32x4 acc_l[2];
  float m_run[2];
  const int q0_hi = qt_hi * 64 + rh * 32;

  if (wv < 2) {
    // ---- low tile, full KV range [0, pp+1), direct store ----
    const int q0_lo = qt_lo * 64 + rh * 32;
    attn_load_q(qf, Qbase, q0_lo, lr, lg);
    attn_init(acc_o, acc_l, m_run);
    attn_run(acc_o, acc_l, m_run, qf, Kbase, Vbase, P32[wv], q0_lo, 0, pp + 1, lr, lg, onesf);
    store_ctx_tile(P32[wv], acc_o, acc_l, Ctx, b, h, q0_lo, ln, lr, lg);

    // ---- high tile part A: KV [0, h0), keep in regs for merge ----
    attn_load_q(qf, Qbase, q0_hi, lr, lg);
    attn_init(acc_o, acc_l, m_run);
    attn_run(acc_o, acc_l, m_run, qf, Kbase, Vbase, P32[wv], q0_hi, 0, h0, lr, lg, onesf);
  } else {
    // ---- high tile part B: KV [h0, 32-pp) incl. diagonal ----
    attn_load_q(qf, Qbase, q0_hi, lr, lg);
    attn_init(acc_o, acc_l, m_run);
    attn_run(acc_o, acc_l, m_run, qf, Kbase, Vbase, P32[wv], q0_hi, h0, NQT - pp, lr, lg, onesf);
    // dump partial (O^T, m, l) to LDS
    const int pidx = wv - 2;
#pragma unroll
    for (int qi = 0; qi < 2; ++qi) {
#pragma unroll
      for (int db = 0; db < 4; ++db)
        *(f32x4*)&O_part[pidx][qi * 16 + lr][16 * db + 4 * lg] = acc_o[qi][db];
      if (lg == 0) {
        ml_part[pidx][qi * 16 + lr][0] = m_run[qi];
        ml_part[pidx][qi * 16 + lr][1] = acc_l[qi][0];
      }
    }
  }

  __syncthreads();

  if (wv < 2) {
    // ---- merge part A (regs) with part B (LDS), store high tile ----
#pragma unroll
    for (int qi = 0; qi < 2; ++qi) {
      float m1 = m_run[qi];
      float m2 = ml_part[wv][qi * 16 + lr][0];
      float mn = fmaxf(m1, m2);
      float a1 = __expf(m1 - mn);
      float a2 = __expf(m2 - mn);
      float l = a1 * acc_l[qi][0] + a2 * ml_part[wv][qi * 16 + lr][1];
#pragma unroll
      for (int db = 0; db < 4; ++db) {
        f32x4 po = *(const f32x4*)&O_part[wv][qi * 16 + lr][16 * db + 4 * lg];
#pragma unroll
        for (int r = 0; r < 4; ++r)
          acc_o[qi][db][r] = a1 * acc_o[qi][db][r] + a2 * po[r];
      }
      acc_l[qi] = (f32x4){l, l, l, l};
    }
    store_ctx_tile(P32[wv], acc_o, acc_l, Ctx, b, h, q0_hi, ln, lr, lg);
  }
}

// ---------------------------------------------------------------------------
extern "C" void kernel_launch(void* const* d_in, const int* in_sizes, int n_in,
                              void* d_out, int out_size, void* d_ws, size_t ws_size,
                              hipStream_t stream) {
  const float* q  = (const float*)d_in[0];
  const float* k  = (const float*)d_in[1];
  const float* v  = (const float*)d_in[2];
  // d_in[3] = additive causal mask — applied analytically in attn_kernel
  const float* bq = (const float*)d_in[5];
  const float* bk = (const float*)d_in[7];
  const float* bv = (const float*)d_in[9];
  const float* bo = (const float*)d_in[11];
  const float* Wq = (const float*)d_in[4];
  const float* Wk = (const float*)d_in[6];
  const float* Wv = (const float*)d_in[8];
  const float* Wo = (const float*)d_in[10];
  float* out = (float*)d_out;

  char* w = (char*)d_ws;
  bf16_t* Aqkv  = (bf16_t*)(w);                       // 3 x [4096][1024] bf16
  bf16_t* WtAll = (bf16_t*)(w + 25165824);            // 4 x [1024][1024] bf16
  bf16_t* Qg    = (bf16_t*)(w + 33554432);            // [4096][1024] bf16
  bf16_t* Kg    = (bf16_t*)(w + 41943040);            // [4096][1024] bf16
  bf16_t* Vt    = (bf16_t*)(w + 50331648);            // [1024][4096] bf16 (V^T)
  bf16_t* Ctx   = (bf16_t*)(w + 58720256);            // [4096][1024] bf16

  cvt_qkv_kernel<<<2048, 256, 0, stream>>>(q, k, v, Aqkv);
  transpose_w_kernel<<<dim3(32, 32, 4), dim3(32, 8), 0, stream>>>(Wq, Wk, Wv, Wo, WtAll);
  qk_proj_kernel<<<dim3(16, 32, 2), 256, 0, stream>>>(
      Aqkv, Aqkv + (size_t)MTOT * D_MODEL, WtAll, bq, bk, Qg, Kg);
  vt_proj_kernel<<<dim3(64, 8), 256, 0, stream>>>(
      WtAll + 2 * (size_t)D_MODEL * D_MODEL, Aqkv + 2 * (size_t)MTOT * D_MODEL, bv, Vt);
  attn_kernel<<<dim3(32, 16), 256, 0, stream>>>(Qg, Kg, Vt, Ctx);
  out_gemm_kernel<<<dim3(16, 32), 256, 0, stream>>>(
      Ctx, WtAll + 3 * (size_t)D_MODEL * D_MODEL, bo, out);
}

// Round 12
// 264.667 us; speedup vs baseline: 1.0605x; 1.0605x over previous
//
#include <hip/hip_runtime.h>
#include <hip/hip_bf16.h>
#include <stdint.h>

typedef __bf16 bf16x8 __attribute__((ext_vector_type(8)));
typedef float  f32x4  __attribute__((ext_vector_type(4)));
typedef __hip_bfloat16 bf16_t;

#define D_MODEL 1024
#define NH 16
#define DH 64
#define BB 2
#define SS 2048
#define MTOT (BB*SS)   /* 4096 */
#define NQT (SS/64)    /* 32 q-tiles per (b,h) */

#define GBM 128
#define GBN 64
#define GBK 64

// ---------------------------------------------------------------------------
// fp32 -> bf16 convert for q,k,v (one launch, 3 tensors)
// ---------------------------------------------------------------------------
__global__ void cvt_qkv_kernel(const float* __restrict__ q, const float* __restrict__ k,
                               const float* __restrict__ v, bf16_t* __restrict__ dst) {
  const int n1v = MTOT * D_MODEL / 4;  // float4 count per tensor
  int tid = blockIdx.x * blockDim.x + threadIdx.x;
  int stride = gridDim.x * blockDim.x;
  for (int i = tid; i < 3 * n1v; i += stride) {
    int which = i / n1v;
    int j = i - which * n1v;
    const float4* src = (const float4*)(which == 0 ? q : (which == 1 ? k : v));
    float4 f = src[j];
    union { bf16_t h[4]; short4 s4; } u;
    u.h[0] = __float2bfloat16(f.x);
    u.h[1] = __float2bfloat16(f.y);
    u.h[2] = __float2bfloat16(f.z);
    u.h[3] = __float2bfloat16(f.w);
    ((short4*)dst)[(size_t)which * n1v + j] = u.s4;
  }
}

// ---------------------------------------------------------------------------
// W [K][N] fp32  ->  Wt [N][K] bf16   (z = 0..3 selects Wq,Wk,Wv,Wo)
// ---------------------------------------------------------------------------
__global__ void transpose_w_kernel(const float* __restrict__ W0, const float* __restrict__ W1,
                                   const float* __restrict__ W2, const float* __restrict__ W3,
                                   bf16_t* __restrict__ WtAll) {
  __shared__ float tile[32][33];
  const int z = blockIdx.z;
  const float* W = (z == 0) ? W0 : (z == 1) ? W1 : (z == 2) ? W2 : W3;
  bf16_t* Wt = WtAll + (size_t)z * D_MODEL * D_MODEL;
  const int tx = threadIdx.x, ty = threadIdx.y;
  const int bx = blockIdx.x, by = blockIdx.y;
#pragma unroll
  for (int i = 0; i < 4; ++i)
    tile[ty + i * 8][tx] = W[(size_t)(by * 32 + ty + i * 8) * D_MODEL + bx * 32 + tx];
  __syncthreads();
#pragma unroll
  for (int i = 0; i < 4; ++i)
    Wt[(size_t)(bx * 32 + ty + i * 8) * D_MODEL + by * 32 + tx] =
        __float2bfloat16(tile[tx][ty + i * 8]);
}

// ---------------------------------------------------------------------------
// GEMM mainloop: C[128x64] tile, DOUBLE-BUFFERED 2-phase (R11, T3 recipe):
// STAGE(next tile -> other buf) issued BEFORE the MFMA cluster; ONE
// __syncthreads per K-step (implicit vmcnt(0) drain = data-ready, barrier =
// buffer-reuse safety). Loads get the whole compute phase to land.
// 4 waves 2x2 over (2x64 M, 2x32 N), each wave 64x32 = 4x2 frags.
// ---------------------------------------------------------------------------
__device__ __forceinline__ void g2lds16(const bf16_t* g, bf16_t* l) {
  __builtin_amdgcn_global_load_lds((__attribute__((address_space(1))) void*)(g),
                                   (__attribute__((address_space(3))) void*)(l), 16, 0, 0);
}

__device__ __forceinline__ void gemm_stage(const bf16_t* __restrict__ A,
                                           const bf16_t* __restrict__ Bt,
                                           bf16_t* As, bf16_t* Bs,
                                           int m0, int n0, int kt, int wv, int ln) {
  const int row8 = ln >> 3;
  const int col = (ln & 7) * 8;
#pragma unroll
  for (int c = 0; c < 6; ++c) {
    int chunk = wv * 6 + c;
    if (chunk < 16) {
      g2lds16(A + (size_t)(m0 + chunk * 8 + row8) * D_MODEL + kt * GBK + col,
              As + chunk * 8 * GBK);
    } else {
      g2lds16(Bt + (size_t)(n0 + (chunk - 16) * 8 + row8) * D_MODEL + kt * GBK + col,
              Bs + (chunk - 16) * 8 * GBK);
    }
  }
}

__device__ __forceinline__ void gemm_tile_mainloop(const bf16_t* __restrict__ A,
                                                   const bf16_t* __restrict__ Bt,
                                                   bf16_t* As, bf16_t* Bs,  // 2 bufs each
                                                   int m0, int n0, f32x4 acc[4][2]) {
  const int tid = threadIdx.x;
  const int wv = tid >> 6, ln = tid & 63;
  const int wr = wv >> 1, wc = wv & 1;
  const int lr = ln & 15, lg = ln >> 4;

#pragma unroll
  for (int mi = 0; mi < 4; ++mi)
#pragma unroll
    for (int ni = 0; ni < 2; ++ni)
      acc[mi][ni] = (f32x4){0.f, 0.f, 0.f, 0.f};

  const int NT = D_MODEL / GBK;  // 16
  gemm_stage(A, Bt, As, Bs, m0, n0, 0, wv, ln);
  __syncthreads();  // buf0 ready

  int cur = 0;
  for (int kt = 0; kt < NT; ++kt) {
    if (kt + 1 < NT)
      gemm_stage(A, Bt, As + (cur ^ 1) * (GBM * GBK), Bs + (cur ^ 1) * (GBN * GBK),
                 m0, n0, kt + 1, wv, ln);
    const bf16_t* Ab = As + cur * (GBM * GBK);
    const bf16_t* Bb = Bs + cur * (GBN * GBK);
#pragma unroll
    for (int ks = 0; ks < 2; ++ks) {
      bf16x8 af[4], bfr[2];
#pragma unroll
      for (int mi = 0; mi < 4; ++mi)
        af[mi] = *(const bf16x8*)(Ab + (size_t)(wr * 64 + mi * 16 + lr) * GBK + ks * 32 + lg * 8);
#pragma unroll
      for (int ni = 0; ni < 2; ++ni)
        bfr[ni] = *(const bf16x8*)(Bb + (size_t)(wc * 32 + ni * 16 + lr) * GBK + ks * 32 + lg * 8);
#pragma unroll
      for (int mi = 0; mi < 4; ++mi)
#pragma unroll
        for (int ni = 0; ni < 2; ++ni)
          acc[mi][ni] = __builtin_amdgcn_mfma_f32_16x16x32_bf16(af[mi], bfr[ni], acc[mi][ni], 0, 0, 0);
    }
    __syncthreads();  // next-buf loads drained + cur-buf reads complete
    cur ^= 1;
  }
}

// ---------------------------------------------------------------------------
// Q/K projection GEMM: z=0 -> Q (x 1/8 softmax scale folded), z=1 -> K.
// ---------------------------------------------------------------------------
__global__ __launch_bounds__(256)
void qk_proj_kernel(const bf16_t* __restrict__ Aq, const bf16_t* __restrict__ Ak,
                    const bf16_t* __restrict__ WtAll,
                    const float* __restrict__ bq, const float* __restrict__ bk,
                    bf16_t* __restrict__ Qg, bf16_t* __restrict__ Kg) {
  __shared__ bf16_t As[2 * GBM * GBK];
  __shared__ bf16_t Bs[2 * GBN * GBK];
  const int z = blockIdx.z;
  const bf16_t* A = (z == 0) ? Aq : Ak;
  const bf16_t* Bt = WtAll + (size_t)z * D_MODEL * D_MODEL;
  const float* bias = (z == 0) ? bq : bk;
  bf16_t* Out = (z == 0) ? Qg : Kg;
  const float scale = (z == 0) ? 0.125f : 1.0f;  // fold 1/sqrt(DH) into Q
  const int m0 = blockIdx.y * GBM, n0 = blockIdx.x * GBN;

  f32x4 acc[4][2];
  gemm_tile_mainloop(A, Bt, As, Bs, m0, n0, acc);

  const int tid = threadIdx.x;
  const int wv = tid >> 6, ln = tid & 63;
  const int wr = wv >> 1, wc = wv & 1;
  const int lr = ln & 15, lg = ln >> 4;

#pragma unroll
  for (int mi = 0; mi < 4; ++mi) {
#pragma unroll
    for (int ni = 0; ni < 2; ++ni) {
      int ncol = n0 + wc * 32 + ni * 16 + lr;
      float bsv = bias[ncol];
#pragma unroll
      for (int j = 0; j < 4; ++j) {
        int mrow = m0 + wr * 64 + mi * 16 + lg * 4 + j;
        Out[(size_t)mrow * D_MODEL + ncol] = __float2bfloat16((acc[mi][ni][j] + bsv) * scale);
      }
    }
  }
}

// ---------------------------------------------------------------------------
// V^T projection GEMM: Vt[d][s_glob] = Wv^T @ Av^T + bv (coalesced stores).
// ---------------------------------------------------------------------------
__global__ __launch_bounds__(256)
void vt_proj_kernel(const bf16_t* __restrict__ Wtv, const bf16_t* __restrict__ Av,
                    const float* __restrict__ bv, bf16_t* __restrict__ Vt) {
  __shared__ bf16_t As[2 * GBM * GBK];
  __shared__ bf16_t Bs[2 * GBN * GBK];
  const int m0 = blockIdx.y * GBM, n0 = blockIdx.x * GBN;

  f32x4 acc[4][2];
  gemm_tile_mainloop(Wtv, Av, As, Bs, m0, n0, acc);

  const int tid = threadIdx.x;
  const int wv = tid >> 6, ln = tid & 63;
  const int wr = wv >> 1, wc = wv & 1;
  const int lr = ln & 15, lg = ln >> 4;

#pragma unroll
  for (int mi = 0; mi < 4; ++mi) {
#pragma unroll
    for (int ni = 0; ni < 2; ++ni) {
      int ncol = n0 + wc * 32 + ni * 16 + lr;
#pragma unroll
      for (int j = 0; j < 4; ++j) {
        int mrow = m0 + wr * 64 + mi * 16 + lg * 4 + j;   // d row
        Vt[(size_t)mrow * MTOT + ncol] = __float2bfloat16(acc[mi][ni][j] + bv[mrow]);
      }
    }
  }
}

// ---------------------------------------------------------------------------
// Output GEMM: ctx[M][K] bf16 @ Wo^T [N][K] bf16 + bo -> fp32 out [M][N]
// ---------------------------------------------------------------------------
__global__ __launch_bounds__(256)
void out_gemm_kernel(const bf16_t* __restrict__ Ctx, const bf16_t* __restrict__ Wto,
                     const float* __restrict__ bo, float* __restrict__ out) {
  __shared__ bf16_t As[2 * GBM * GBK];
  __shared__ bf16_t Bs[2 * GBN * GBK];
  const int m0 = blockIdx.y * GBM, n0 = blockIdx.x * GBN;

  f32x4 acc[4][2];
  gemm_tile_mainloop(Ctx, Wto, As, Bs, m0, n0, acc);

  const int tid = threadIdx.x;
  const int wv = tid >> 6, ln = tid & 63;
  const int wr = wv >> 1, wc = wv & 1;
  const int lr = ln & 15, lg = ln >> 4;

#pragma unroll
  for (int mi = 0; mi < 4; ++mi) {
#pragma unroll
    for (int ni = 0; ni < 2; ++ni) {
      int ncol = n0 + wc * 32 + ni * 16 + lr;
      float bsv = bo[ncol];
#pragma unroll
      for (int j = 0; j < 4; ++j) {
        int mrow = m0 + wr * 64 + mi * 16 + lg * 4 + j;
        out[(size_t)mrow * D_MODEL + ncol] = acc[mi][ni][j] + bsv;
      }
    }
  }
}

// ---------------------------------------------------------------------------
// Flash attention, causal — SWAPPED-QK^T structure (unchanged from R10).
// ---------------------------------------------------------------------------
__device__ __forceinline__ uint32_t pack2bf(float a, float b) {
  union { __hip_bfloat16 h; unsigned short u; } ua, ub;
  ua.h = __float2bfloat16(a);
  ub.h = __float2bfloat16(b);
  return (uint32_t)ua.u | ((uint32_t)ub.u << 16);
}

#define PSTRIDE 44  /* dwords per P row: conflict-tuned, 16B-multiple (176B) */

__device__ __forceinline__ void attn_run(
    f32x4 acc_o[2][4], f32x4 acc_l[2], float m_run[2],
    const bf16x8 qf[2][2], const bf16_t* Kbase, const bf16_t* Vbase,
    uint32_t (*P32)[PSTRIDE], int q0, int t0, int t1, int lr, int lg, bf16x8 onesf) {
  // prologue: K fragments for first tile
  bf16x8 kf_cur[2][4];
#pragma unroll
  for (int ks = 0; ks < 2; ++ks)
#pragma unroll
    for (int kb = 0; kb < 4; ++kb)
      kf_cur[ks][kb] = *(const bf16x8*)(Kbase + (size_t)(t0 * 64 + kb * 16 + lr) * D_MODEL + ks * 32 + lg * 8);

  for (int t = t0; t < t1; ++t) {
    const int kv0 = t * 64;
    f32x4 sc[2][4];
#pragma unroll
    for (int qi = 0; qi < 2; ++qi)
#pragma unroll
      for (int kb = 0; kb < 4; ++kb) sc[qi][kb] = (f32x4){0.f, 0.f, 0.f, 0.f};

    // S^T = K Q^T : C[kv][q], q-col = lane&15
    __builtin_amdgcn_s_setprio(1);
#pragma unroll
    for (int ks = 0; ks < 2; ++ks) {
#pragma unroll
      for (int kb = 0; kb < 4; ++kb) {
        sc[0][kb] = __builtin_amdgcn_mfma_f32_16x16x32_bf16(kf_cur[ks][kb], qf[0][ks], sc[0][kb], 0, 0, 0);
        sc[1][kb] = __builtin_amdgcn_mfma_f32_16x16x32_bf16(kf_cur[ks][kb], qf[1][ks], sc[1][kb], 0, 0, 0);
      }
    }
    __builtin_amdgcn_s_setprio(0);

    // prefetch K(t+1)
    bf16x8 kf_nxt[2][4];
    if (t + 1 < t1) {
#pragma unroll
      for (int ks = 0; ks < 2; ++ks)
#pragma unroll
        for (int kb = 0; kb < 4; ++kb)
          kf_nxt[ks][kb] = *(const bf16x8*)(Kbase + (size_t)(kv0 + 64 + kb * 16 + lr) * D_MODEL + ks * 32 + lg * 8);
    }
    // prefetch V(t): V^T fragment, row d = db*16+lr, k = kv
    bf16x8 vf[2][4];
#pragma unroll
    for (int ks = 0; ks < 2; ++ks)
#pragma unroll
      for (int db = 0; db < 4; ++db)
        vf[ks][db] = *(const bf16x8*)(Vbase + (size_t)(db * 16 + lr) * MTOT + kv0 + ks * 32 + lg * 8);

    // causal mask: kc = kv0+16kb+4lg+r, qc = q0+qi*16+lr
    if (kv0 + 63 > q0) {
#pragma unroll
      for (int qi = 0; qi < 2; ++qi) {
        int qc = q0 + qi * 16 + lr;
#pragma unroll
        for (int kb = 0; kb < 4; ++kb)
#pragma unroll
          for (int r = 0; r < 4; ++r) {
            int kc = kv0 + kb * 16 + 4 * lg + r;
            if (kc > qc) sc[qi][kb][r] = -1e30f;
          }
      }
    }

    // lane-local softmax per q-column
#pragma unroll
    for (int qi = 0; qi < 2; ++qi) {
      float vm = sc[qi][0][0];
#pragma unroll
      for (int kb = 0; kb < 4; ++kb)
#pragma unroll
        for (int r = 0; r < 4; ++r) vm = fmaxf(vm, sc[qi][kb][r]);
      vm = fmaxf(vm, __shfl_xor(vm, 16, 64));
      vm = fmaxf(vm, __shfl_xor(vm, 32, 64));
      float mo = m_run[qi];
      float mn = fmaxf(mo, vm);
      float scl = __expf(mo - mn);
      m_run[qi] = mn;
#pragma unroll
      for (int kb = 0; kb < 4; ++kb)
#pragma unroll
        for (int hh = 0; hh < 2; ++hh) {
          float p0 = __expf(sc[qi][kb][2 * hh]     - mn);
          float p1 = __expf(sc[qi][kb][2 * hh + 1] - mn);
          P32[qi * 16 + lr][8 * kb + 2 * lg + hh] = pack2bf(p0, p1);
        }
#pragma unroll
      for (int r = 0; r < 4; ++r) acc_l[qi][r] *= scl;
#pragma unroll
      for (int db = 0; db < 4; ++db)
#pragma unroll
        for (int r = 0; r < 4; ++r) acc_o[qi][db][r] *= scl;
    }

    // wave-internal LDS turnaround (rule #18 discipline)
    asm volatile("s_waitcnt lgkmcnt(0)" ::: "memory");
    __builtin_amdgcn_sched_barrier(0);

    // P^T fragments: B-operand needs [k=kv=32ks+8lg+j][col=q=lane&15]
    bf16x8 pb[2][2];
#pragma unroll
    for (int qi = 0; qi < 2; ++qi)
#pragma unroll
      for (int ks = 0; ks < 2; ++ks)
        pb[qi][ks] = *(const bf16x8*)&P32[qi * 16 + lr][16 * ks + 4 * lg];

    // O^T += V^T P^T ; l += ones * P^T
    __builtin_amdgcn_s_setprio(1);
#pragma unroll
    for (int ks = 0; ks < 2; ++ks) {
#pragma unroll
      for (int qi = 0; qi < 2; ++qi) {
        acc_l[qi] = __builtin_amdgcn_mfma_f32_16x16x32_bf16(onesf, pb[qi][ks], acc_l[qi], 0, 0, 0);
#pragma unroll
        for (int db = 0; db < 4; ++db)
          acc_o[qi][db] = __builtin_amdgcn_mfma_f32_16x16x32_bf16(vf[ks][db], pb[qi][ks], acc_o[qi][db], 0, 0, 0);
      }
    }
    __builtin_amdgcn_s_setprio(0);

    if (t + 1 < t1) {
#pragma unroll
      for (int ks = 0; ks < 2; ++ks)
#pragma unroll
        for (int kb = 0; kb < 4; ++kb)
          kf_cur[ks][kb] = kf_nxt[ks][kb];
    }
  }
}

__device__ __forceinline__ void attn_load_q(bf16x8 qf[2][2], const bf16_t* Qbase,
                                            int q0, int lr, int lg) {
#pragma unroll
  for (int qi = 0; qi < 2; ++qi)
#pragma unroll
    for (int ks = 0; ks < 2; ++ks)
      qf[qi][ks] = *(const bf16x8*)(Qbase + (size_t)(q0 + qi * 16 + lr) * D_MODEL + ks * 32 + lg * 8);
}

__device__ __forceinline__ void attn_init(f32x4 acc_o[2][4], f32x4 acc_l[2], float m_run[2]) {
#pragma unroll
  for (int qi = 0; qi < 2; ++qi) {
#pragma unroll
    for (int db = 0; db < 4; ++db) acc_o[qi][db] = (f32x4){0.f, 0.f, 0.f, 0.f};
    acc_l[qi] = (f32x4){0.f, 0.f, 0.f, 0.f};
    m_run[qi] = -1e30f;
  }
}

// O^T regs -> bf16 LDS bounce -> coalesced row-major store (64B segments)
__device__ __forceinline__ void store_ctx_tile(
    uint32_t (*P32)[PSTRIDE], const f32x4 acc_o[2][4], const f32x4 acc_l[2],
    bf16_t* __restrict__ Ctx, int b, int h, int q0, int ln, int lr, int lg) {
#pragma unroll
  for (int qi = 0; qi < 2; ++qi) {
    float rl = 1.0f / acc_l[qi][0];
#pragma unroll
    for (int db = 0; db < 4; ++db)
#pragma unroll
      for (int hh = 0; hh < 2; ++hh)
        P32[qi * 16 + lr][8 * db + 2 * lg + hh] =
            pack2bf(acc_o[qi][db][2 * hh] * rl, acc_o[qi][db][2 * hh + 1] * rl);
  }
  asm volatile("s_waitcnt lgkmcnt(0)" ::: "memory");
  __builtin_amdgcn_sched_barrier(0);
#pragma unroll
  for (int c = 0; c < 4; ++c) {
    int row = (ln >> 2) + 16 * (c >> 1);
    int dwc = (ln & 3) * 4 + 16 * (c & 1);
    bf16x8 v = *(const bf16x8*)&P32[row][dwc];
    *(bf16x8*)(Ctx + (size_t)(b * SS + q0 + row) * D_MODEL + h * DH + dwc * 2) = v;
  }
}

__global__ __launch_bounds__(256)
void attn_kernel(const bf16_t* __restrict__ Qg, const bf16_t* __restrict__ Kg,
                 const bf16_t* __restrict__ Vt, bf16_t* __restrict__ Ctx) {
  __shared__ __align__(16) uint32_t P32[4][32][PSTRIDE];
  __shared__ __align__(16) float O_part[2][32][68];   // partial O^T, [q][d]+pad
  __shared__ float ml_part[2][32][2];                 // [q][0]=m, [1]=l
  const int bh = blockIdx.x;
  const int pp = blockIdx.y;
  const int b = bh >> 4, h = bh & 15;
  const int wv = threadIdx.x >> 6, ln = threadIdx.x & 63;
  const int lr = ln & 15, lg = ln >> 4;

  const int qt_lo = pp, qt_hi = NQT - 1 - pp;
  const int h0 = 16 - pp;                 // high tile KV split point
  const int rh = wv & 1;                  // row half within the 64-row tile

  const size_t qkbase = (size_t)b * SS * D_MODEL + (size_t)h * DH;
  const bf16_t* Qbase = Qg + qkbase;
  const bf16_t* Kbase = Kg + qkbase;
  const bf16_t* Vbase = Vt + (size_t)(h * DH) * MTOT + b * SS;

  bf16x8 onesf;
#pragma unroll
  for (int j = 0; j < 8; ++j) onesf[j] = (__bf16)1.0f;

  bf16x8 qf[2][2];
  f32x4 acc_o[2][4];
  f32x4 acc_l[2];
  float m_run[2];
  const int q0_hi = qt_hi * 64 + rh * 32;

  if (wv < 2) {
    // ---- low tile, full KV range [0, pp+1), direct store ----
    const int q0_lo = qt_lo * 64 + rh * 32;
    attn_load_q(qf, Qbase, q0_lo, lr, lg);
    attn_init(acc_o, acc_l, m_run);
    attn_run(acc_o, acc_l, m_run, qf, Kbase, Vbase, P32[wv], q0_lo, 0, pp + 1, lr, lg, onesf);
    store_ctx_tile(P32[wv], acc_o, acc_l, Ctx, b, h, q0_lo, ln, lr, lg);

    // ---- high tile part A: KV [0, h0), keep in regs for merge ----
    attn_load_q(qf, Qbase, q0_hi, lr, lg);
    attn_init(acc_o, acc_l, m_run);
    attn_run(acc_o, acc_l, m_run, qf, Kbase, Vbase, P32[wv], q0_hi, 0, h0, lr, lg, onesf);
  } else {
    // ---- high tile part B: KV [h0, 32-pp) incl. diagonal ----
    attn_load_q(qf, Qbase, q0_hi, lr, lg);
    attn_init(acc_o, acc_l, m_run);
    attn_run(acc_o, acc_l, m_run, qf, Kbase, Vbase, P32[wv], q0_hi, h0, NQT - pp, lr, lg, onesf);
    // dump partial (O^T, m, l) to LDS
    const int pidx = wv - 2;
#pragma unroll
    for (int qi = 0; qi < 2; ++qi) {
#pragma unroll
      for (int db = 0; db < 4; ++db)
        *(f32x4*)&O_part[pidx][qi * 16 + lr][16 * db + 4 * lg] = acc_o[qi][db];
      if (lg == 0) {
        ml_part[pidx][qi * 16 + lr][0] = m_run[qi];
        ml_part[pidx][qi * 16 + lr][1] = acc_l[qi][0];
      }
    }
  }

  __syncthreads();

  if (wv < 2) {
    // ---- merge part A (regs) with part B (LDS), store high tile ----
#pragma unroll
    for (int qi = 0; qi < 2; ++qi) {
      float m1 = m_run[qi];
      float m2 = ml_part[wv][qi * 16 + lr][0];
      float mn = fmaxf(m1, m2);
      float a1 = __expf(m1 - mn);
      float a2 = __expf(m2 - mn);
      float l = a1 * acc_l[qi][0] + a2 * ml_part[wv][qi * 16 + lr][1];
#pragma unroll
      for (int db = 0; db < 4; ++db) {
        f32x4 po = *(const f32x4*)&O_part[wv][qi * 16 + lr][16 * db + 4 * lg];
#pragma unroll
        for (int r = 0; r < 4; ++r)
          acc_o[qi][db][r] = a1 * acc_o[qi][db][r] + a2 * po[r];
      }
      acc_l[qi] = (f32x4){l, l, l, l};
    }
    store_ctx_tile(P32[wv], acc_o, acc_l, Ctx, b, h, q0_hi, ln, lr, lg);
  }
}

// ---------------------------------------------------------------------------
extern "C" void kernel_launch(void* const* d_in, const int* in_sizes, int n_in,
                              void* d_out, int out_size, void* d_ws, size_t ws_size,
                              hipStream_t stream) {
  const float* q  = (const float*)d_in[0];
  const float* k  = (const float*)d_in[1];
  const float* v  = (const float*)d_in[2];
  // d_in[3] = additive causal mask — applied analytically in attn_kernel
  const float* bq = (const float*)d_in[5];
  const float* bk = (const float*)d_in[7];
  const float* bv = (const float*)d_in[9];
  const float* bo = (const float*)d_in[11];
  const float* Wq = (const float*)d_in[4];
  const float* Wk = (const float*)d_in[6];
  const float* Wv = (const float*)d_in[8];
  const float* Wo = (const float*)d_in[10];
  float* out = (float*)d_out;

  char* w = (char*)d_ws;
  bf16_t* Aqkv  = (bf16_t*)(w);                       // 3 x [4096][1024] bf16
  bf16_t* WtAll = (bf16_t*)(w + 25165824);            // 4 x [1024][1024] bf16
  bf16_t* Qg    = (bf16_t*)(w + 33554432);            // [4096][1024] bf16
  bf16_t* Kg    = (bf16_t*)(w + 41943040);            // [4096][1024] bf16
  bf16_t* Vt    = (bf16_t*)(w + 50331648);            // [1024][4096] bf16 (V^T)
  bf16_t* Ctx   = (bf16_t*)(w + 58720256);            // [4096][1024] bf16

  cvt_qkv_kernel<<<2048, 256, 0, stream>>>(q, k, v, Aqkv);
  transpose_w_kernel<<<dim3(32, 32, 4), dim3(32, 8), 0, stream>>>(Wq, Wk, Wv, Wo, WtAll);
  qk_proj_kernel<<<dim3(16, 32, 2), 256, 0, stream>>>(
      Aqkv, Aqkv + (size_t)MTOT * D_MODEL, WtAll, bq, bk, Qg, Kg);
  vt_proj_kernel<<<dim3(64, 8), 256, 0, stream>>>(
      WtAll + 2 * (size_t)D_MODEL * D_MODEL, Aqkv + 2 * (size_t)MTOT * D_MODEL, bv, Vt);
  attn_kernel<<<dim3(32, 16), 256, 0, stream>>>(Qg, Kg, Vt, Ctx);
  out_gemm_kernel<<<dim3(16, 32), 256, 0, stream>>>(
      Ctx, WtAll + 3 * (size_t)D_MODEL * D_MODEL, bo, out);
}